// Round 19
// baseline (578.503 us; speedup 1.0000x reference)
//
#include <hip/hip_runtime.h>

#define ALPHA 0.9f
#define BETA  0.8f
#define K     25
#define B     128
#define T     16
#define IN_DIM 14400
#define NSL   8      // batch slices (= XCDs)
#define SW    16     // batch elems per slice
#define CF    96     // features per transpose tile
#define NCH   150    // IN_DIM / CF
// bf16 paired-t row: [feature][2][16] bf16 = 64B; serves TWO timesteps.
// Gather: 4 lanes/neuron (parity x octet), ushort8 16B/lane -> one wave-load
// covers 16 complete rows serving 2 timesteps = half the instructions of
// r18's kernels. Time tracks instrs at ~1.9cy/instr (r18 analysis).

using u16 = unsigned short;
typedef __attribute__((ext_vector_type(8))) unsigned short ushort8;

static __device__ __forceinline__ u16 f2bf(float f) {
  union { float f; unsigned u; } c; c.f = f;
  const unsigned r = c.u + 0x7FFFu + ((c.u >> 16) & 1u);  // RTNE
  return (u16)(r >> 16);
}
static __device__ __forceinline__ float bf2f(u16 h) {
  union { unsigned u; float f; } c; c.u = ((unsigned)h) << 16;
  return c.f;
}

// ---------------------------------------------------------------------------
// Slice-pinned pair-complete transpose (r13, proven clean). x slab [t0,t0+8)
// fp32 -> bf16 xTh[4tp][8e][IN][2][16]; every 64B row written complete by
// the owning XCD. Grid 1024 = residency at LB(256,4).
// ---------------------------------------------------------------------------
__global__ __launch_bounds__(256, 4) void transpose_pair_pinned(
    const float* __restrict__ x, u16* __restrict__ xTh, int t0, int slots) {
  __shared__ float lds[CF][33];
  const int e    = blockIdx.x & 7;
  const int slot = blockIdx.x >> 3;
  const int tid  = threadIdx.x;
  const int rid  = tid >> 3;        // 0..31
  const int fq   = tid & 7;
  const int tpar = rid >> 4;        // t parity
  const int bl   = rid & 15;
  const int b    = e * 16 + bl;

  const int ntiles = 4 * NCH;
  for (int ti = slot; ti < ntiles; ti += slots) {
    const int tp = ti / NCH;
    const int ch = ti - tp * NCH;
    const int i0 = ch * CF;
    const int t  = t0 + tp * 2 + tpar;
    const float* xr = x + ((size_t)b * T + t) * IN_DIM + i0;
#pragma unroll
    for (int pf = 0; pf < CF / 32; ++pf) {
      const float4 v = *(const float4*)&xr[pf * 32 + fq * 4];
      lds[pf * 32 + fq * 4 + 0][rid] = v.x;
      lds[pf * 32 + fq * 4 + 1][rid] = v.y;
      lds[pf * 32 + fq * 4 + 2][rid] = v.z;
      lds[pf * 32 + fq * 4 + 3][rid] = v.w;
    }
    __syncthreads();
#pragma unroll
    for (int wp = 0; wp < CF / 32; ++wp) {
      const int f = wp * 32 + rid;
      ushort4 ov;
      ov.x = f2bf(lds[f][fq * 4 + 0]);
      ov.y = f2bf(lds[f][fq * 4 + 1]);
      ov.z = f2bf(lds[f][fq * 4 + 2]);
      ov.w = f2bf(lds[f][fq * 4 + 3]);
      *(ushort4*)&xTh[(((size_t)tp * NSL + e) * IN_DIM + (i0 + f)) * 32 +
                      fq * 4] = ov;
    }
    __syncthreads();
  }
}

// ---------------------------------------------------------------------------
// Fused LCN+LIF, bf16 t-paired rows, ushort8 16B gathers, 32 neurons x 4
// lanes = 128 thr. LB(128,4) -> VGPR cap 128 (the r16 version of this scheme
// spilled at 64-reg alloc: 256-thr 64-neuron blocks; live set here ~95 regs
// fits). knn/w staged in LDS (6.4 KB). 8 blocks/CU -> residency 2048 >= all
// grids (L0 1800) so blockIdx%8 = XCD launch-exact.
// LIF parity pair resolved via __shfl_xor(2); state fp32 in registers.
// ---------------------------------------------------------------------------
template <int NTP>
__global__ __launch_bounds__(128, 4) void lcn16v2(
    const u16* __restrict__ hsrc, const float* __restrict__ w,
    const float* __restrict__ bias, const int* __restrict__ knn,
    u16* __restrict__ memout, float* __restrict__ state,
    int dim, int dprev, int load_state, int save_state) {
  __shared__ int   sidx[32][K];
  __shared__ float swr[32][K];

  const int e    = blockIdx.x & 7;        // slice -> XCD
  const int blk  = blockIdx.x >> 3;
  const int nl   = threadIdx.x >> 2;      // neuron in block (0..31)
  const int l4   = threadIdx.x & 3;
  const int half = l4 >> 1;               // t parity
  const int oct  = l4 & 1;                // batch octet (8 elems)
  const int lofs = half * SW + oct * 8;   // u16 offset within paired row

  const int dd  = blk * 32 + nl;
  const bool act = dd < dim;
  const int d   = act ? dd : dim - 1;

  for (int i = threadIdx.x; i < 32 * K; i += 128) {
    const int n = i / K, k = i - n * K;
    int dn = blk * 32 + n;
    if (dn >= dim) dn = dim - 1;
    sidx[n][k] = knn[dn * K + k] * 32;
    swr[n][k]  = w[dn * K + k];
  }
  __syncthreads();

  const float bi = bias[d];

  float4 sL = make_float4(0.f, 0.f, 0.f, 0.f), sH = sL, mL = sL, mH = sL;
  if (load_state) {
    const size_t so = ((size_t)e * dim + d) * SW + oct * 8;
    sL = *(const float4*)&state[so];
    sH = *(const float4*)&state[so + 4];
    mL = *(const float4*)&state[(size_t)NSL * dim * SW + so];
    mH = *(const float4*)&state[(size_t)NSL * dim * SW + so + 4];
  }

#define FMA8(wk, hv)                                 \
  do {                                               \
    aL.x = fmaf(wk, bf2f((hv)[0]), aL.x);            \
    aL.y = fmaf(wk, bf2f((hv)[1]), aL.y);            \
    aL.z = fmaf(wk, bf2f((hv)[2]), aL.z);            \
    aL.w = fmaf(wk, bf2f((hv)[3]), aL.w);            \
    aH.x = fmaf(wk, bf2f((hv)[4]), aH.x);            \
    aH.y = fmaf(wk, bf2f((hv)[5]), aH.y);            \
    aH.z = fmaf(wk, bf2f((hv)[6]), aH.z);            \
    aH.w = fmaf(wk, bf2f((hv)[7]), aH.w);            \
  } while (0)

  for (int tp = 0; tp < NTP; ++tp) {
    const u16* hp = hsrc + ((size_t)tp * NSL + e) * dprev * 32;
    ushort8 ha[5], hb[5];
#pragma unroll
    for (int j = 0; j < 5; ++j) ha[j] = *(const ushort8*)&hp[sidx[nl][j] + lofs];
#pragma unroll
    for (int j = 0; j < 5; ++j) hb[j] = *(const ushort8*)&hp[sidx[nl][5 + j] + lofs];
    float4 aL = make_float4(bi, bi, bi, bi);
    float4 aH = make_float4(bi, bi, bi, bi);
#pragma unroll
    for (int j = 0; j < 5; ++j) FMA8(swr[nl][j], ha[j]);
#pragma unroll
    for (int j = 0; j < 5; ++j) ha[j] = *(const ushort8*)&hp[sidx[nl][10 + j] + lofs];
#pragma unroll
    for (int j = 0; j < 5; ++j) FMA8(swr[nl][5 + j], hb[j]);
#pragma unroll
    for (int j = 0; j < 5; ++j) hb[j] = *(const ushort8*)&hp[sidx[nl][15 + j] + lofs];
#pragma unroll
    for (int j = 0; j < 5; ++j) FMA8(swr[nl][10 + j], ha[j]);
#pragma unroll
    for (int j = 0; j < 5; ++j) ha[j] = *(const ushort8*)&hp[sidx[nl][20 + j] + lofs];
#pragma unroll
    for (int j = 0; j < 5; ++j) FMA8(swr[nl][15 + j], hb[j]);
#pragma unroll
    for (int j = 0; j < 5; ++j) FMA8(swr[nl][20 + j], ha[j]);

    // exchange parities within the (neuron, octet) pair: lane ^ 2
    float4 oL, oH;
    oL.x = __shfl_xor(aL.x, 2, 64);
    oL.y = __shfl_xor(aL.y, 2, 64);
    oL.z = __shfl_xor(aL.z, 2, 64);
    oL.w = __shfl_xor(aL.w, 2, 64);
    oH.x = __shfl_xor(aH.x, 2, 64);
    oH.y = __shfl_xor(aH.y, 2, 64);
    oH.z = __shfl_xor(aH.z, 2, 64);
    oH.w = __shfl_xor(aH.w, 2, 64);
    const float4 p0L = half ? oL : aL;  // t even
    const float4 p0H = half ? oH : aH;
    const float4 p1L = half ? aL : oL;  // t odd
    const float4 p1H = half ? aH : oH;

    // LIF t-even (reset from PREVIOUS membrane)
    sL.x = ALPHA * sL.x + p0L.x;  sL.y = ALPHA * sL.y + p0L.y;
    sL.z = ALPHA * sL.z + p0L.z;  sL.w = ALPHA * sL.w + p0L.w;
    sH.x = ALPHA * sH.x + p0H.x;  sH.y = ALPHA * sH.y + p0H.y;
    sH.z = ALPHA * sH.z + p0H.z;  sH.w = ALPHA * sH.w + p0H.w;
    float4 meL, meH;
    meL.x = BETA * mL.x + sL.x - ((mL.x > 1.0f) ? 1.0f : 0.0f);
    meL.y = BETA * mL.y + sL.y - ((mL.y > 1.0f) ? 1.0f : 0.0f);
    meL.z = BETA * mL.z + sL.z - ((mL.z > 1.0f) ? 1.0f : 0.0f);
    meL.w = BETA * mL.w + sL.w - ((mL.w > 1.0f) ? 1.0f : 0.0f);
    meH.x = BETA * mH.x + sH.x - ((mH.x > 1.0f) ? 1.0f : 0.0f);
    meH.y = BETA * mH.y + sH.y - ((mH.y > 1.0f) ? 1.0f : 0.0f);
    meH.z = BETA * mH.z + sH.z - ((mH.z > 1.0f) ? 1.0f : 0.0f);
    meH.w = BETA * mH.w + sH.w - ((mH.w > 1.0f) ? 1.0f : 0.0f);
    // LIF t-odd
    sL.x = ALPHA * sL.x + p1L.x;  sL.y = ALPHA * sL.y + p1L.y;
    sL.z = ALPHA * sL.z + p1L.z;  sL.w = ALPHA * sL.w + p1L.w;
    sH.x = ALPHA * sH.x + p1H.x;  sH.y = ALPHA * sH.y + p1H.y;
    sH.z = ALPHA * sH.z + p1H.z;  sH.w = ALPHA * sH.w + p1H.w;
    mL.x = BETA * meL.x + sL.x - ((meL.x > 1.0f) ? 1.0f : 0.0f);
    mL.y = BETA * meL.y + sL.y - ((meL.y > 1.0f) ? 1.0f : 0.0f);
    mL.z = BETA * meL.z + sL.z - ((meL.z > 1.0f) ? 1.0f : 0.0f);
    mL.w = BETA * meL.w + sL.w - ((meL.w > 1.0f) ? 1.0f : 0.0f);
    mH.x = BETA * meH.x + sH.x - ((meH.x > 1.0f) ? 1.0f : 0.0f);
    mH.y = BETA * meH.y + sH.y - ((meH.y > 1.0f) ? 1.0f : 0.0f);
    mH.z = BETA * meH.z + sH.z - ((meH.z > 1.0f) ? 1.0f : 0.0f);
    mH.w = BETA * meH.w + sH.w - ((meH.w > 1.0f) ? 1.0f : 0.0f);

    if (act) {
      const float4 wvL = half ? mL : meL;  // this lane's parity
      const float4 wvH = half ? mH : meH;
      ushort8 ov;
      ov[0] = f2bf(wvL.x); ov[1] = f2bf(wvL.y);
      ov[2] = f2bf(wvL.z); ov[3] = f2bf(wvL.w);
      ov[4] = f2bf(wvH.x); ov[5] = f2bf(wvH.y);
      ov[6] = f2bf(wvH.z); ov[7] = f2bf(wvH.w);
      *(ushort8*)&memout[(((size_t)tp * NSL + e) * dim + d) * 32 + lofs] = ov;
    }
  }
#undef FMA8

  if (save_state && act && half == 0) {
    const size_t so = ((size_t)e * dim + d) * SW + oct * 8;
    *(float4*)&state[so] = sL;
    *(float4*)&state[so + 4] = sH;
    *(float4*)&state[(size_t)NSL * dim * SW + so] = mL;
    *(float4*)&state[(size_t)NSL * dim * SW + so + 4] = mH;
  }
}

// Final FC on t=15 (pair 7, odd half) of mem4: [8tp][8e][450][2][16] bf16.
__global__ __launch_bounds__(128) void fc_kernel(
    const u16* __restrict__ mem4, const float* __restrict__ fc_w,
    const float* __restrict__ fc_b, float* __restrict__ out) {
  const int b  = threadIdx.x;
  const int e  = b >> 4;
  const int bl = b & 15;
  float a0 = fc_b[0], a1 = fc_b[1];
  const u16* base = mem4 + ((size_t)7 * NSL + e) * 450 * 32;
  for (int d = 0; d < 450; ++d) {
    const float h = bf2f(base[(size_t)d * 32 + SW + bl]);
    a0 += fc_w[d] * h;
    a1 += fc_w[450 + d] * h;
  }
  out[b * 2 + 0] = a0;
  out[b * 2 + 1] = a1;
}

extern "C" void kernel_launch(void* const* d_in, const int* in_sizes, int n_in,
                              void* d_out, int out_size, void* d_ws,
                              size_t ws_size, hipStream_t stream) {
  (void)in_sizes; (void)n_in; (void)out_size; (void)ws_size;
  const float* x = (const float*)d_in[0];
  const float* w[5];
  const float* bias[5];
  const int* knn[5];
  for (int i = 0; i < 5; ++i) {
    w[i]    = (const float*)d_in[1 + 3 * i];
    bias[i] = (const float*)d_in[2 + 3 * i];
    knn[i]  = (const int*)d_in[3 + 3 * i];
  }
  const float* fc_w = (const float*)d_in[16];
  const float* fc_b = (const float*)d_in[17];
  float* out = (float*)d_out;

  // Workspace: bf16 traces (paired layout [tp][8][d][2][16]) + fp32 state.
  //   A  : 14,745,600 u16  (mem0 [8tp][8][7200][32]; later mem2, mem4)
  //   XB : 14,745,600 u16  (xT half-slab [4tp]; later mem1 + mem3)
  //   S  : 2*8*7200*16 fp32 (layer-0 syn/mem carry between stages)
  u16* A  = (u16*)d_ws;
  u16* XB = A + 14745600;
  float* S = (float*)(XB + 14745600);

  u16* mem0 = A;
  u16* mem1 = XB;
  u16* mem2 = A;
  u16* mem3 = XB + 7372800;
  u16* mem4 = A;

  // ---- Layer 0 in two 8-t (4-pair) stages (xT half-slab reuse) ----
  for (int stage = 0; stage < 2; ++stage) {
    const int t0 = stage * 8;
    transpose_pair_pinned<<<128 * NSL, 256, 0, stream>>>(x, XB, t0, 128);
    lcn16v2<4><<<225 * NSL, 128, 0, stream>>>(
        XB, w[0], bias[0], knn[0], mem0 + (size_t)stage * 7372800, S,
        7200, IN_DIM, /*load=*/stage, /*save=*/stage == 0);
  }

  // ---- Layers 1..4, 8 pairs each, single dispatch ----
  lcn16v2<8><<<113 * NSL, 128, 0, stream>>>(mem0, w[1], bias[1], knn[1],
                                            mem1, nullptr, 3600, 7200, 0, 0);
  lcn16v2<8><<<57 * NSL, 128, 0, stream>>>(mem1, w[2], bias[2], knn[2],
                                           mem2, nullptr, 1800, 3600, 0, 0);
  lcn16v2<8><<<29 * NSL, 128, 0, stream>>>(mem2, w[3], bias[3], knn[3],
                                           mem3, nullptr, 900, 1800, 0, 0);
  lcn16v2<8><<<15 * NSL, 128, 0, stream>>>(mem3, w[4], bias[4], knn[4],
                                           mem4, nullptr, 450, 900, 0, 0);

  fc_kernel<<<1, 128, 0, stream>>>(mem4, fc_w, fc_b, out);
}